// Round 15
// baseline (123.540 us; speedup 1.0000x reference)
//
#include <hip/hip_runtime.h>
#include <hip/hip_bf16.h>

#define B_ 32
#define T_ 1024
#define D_ 128
#define H_ 4
#define DH_ 32

typedef unsigned short ushort_t;
typedef unsigned int uint_t;
typedef unsigned short ushort4_t __attribute__((ext_vector_type(4)));
typedef unsigned short ushort8_t __attribute__((ext_vector_type(8)));
typedef short short8_t __attribute__((ext_vector_type(8)));
typedef float float4_t __attribute__((ext_vector_type(4)));
typedef unsigned int uint4_t __attribute__((ext_vector_type(4)));

__device__ __forceinline__ ushort_t f2bf_bits(float f) {
    __hip_bfloat16 h = __float2bfloat16(f);
    return *reinterpret_cast<ushort_t*>(&h);
}
// pack trunc-bf16(hi)<<16 | trunc-bf16(lo) in one v_perm_b32
__device__ __forceinline__ uint_t pk_bf16(float hi, float lo) {
    return __builtin_amdgcn_perm(__float_as_uint(hi), __float_as_uint(lo),
                                 0x07060302u);
}
#if __has_builtin(__builtin_amdgcn_exp2f)
__device__ __forceinline__ float fast_exp2(float x) { return __builtin_amdgcn_exp2f(x); }
#else
__device__ __forceinline__ float fast_exp2(float x) { return exp2f(x); }
#endif

// ---------------- Kernel 1: MFMA QKV projection, 32 rows/wave --------------
// R14 version (x staged via LDS; raw W + pk_bf16; chunk-fragment V layout;
// tail blocks write Wo in MFMA-fragment layout). Unchanged this round.
__global__ __launch_bounds__(256) void qkv_mfma(
    const float* __restrict__ x, const float* __restrict__ W,
    const float* __restrict__ Wo,
    __hip_bfloat16* __restrict__ qws, __hip_bfloat16* __restrict__ kws,
    __hip_bfloat16* __restrict__ vtws, ushort_t* __restrict__ Wot)
{
    __shared__ ushort_t xst[64][136];      // 17408 B staged x (bf16)
    __shared__ ushort_t qkA[2][16 * 200];
    __shared__ ushort_t qkB[2][16 * 72];

    if (blockIdx.x >= 512) {   // grid tail: Wo -> fragment layout (8 blocks)
        const int t = (blockIdx.x - 512) * 256 + threadIdx.x;  // 0..2047
        const int nt = t >> 8, kc = (t >> 6) & 3, lane = t & 63;
        const int tq = lane >> 4, ti = lane & 15;
        const int n = nt * 16 + ti;
        // frag element j = Wo[kc*32 + tq*8 + j][n], j=0..7
        const float* wo = Wo + (size_t)(kc * 32 + tq * 8) * 128 + n;
        ushort4_t a, b2;
        a[0]  = f2bf_bits(wo[0 * 128]); a[1]  = f2bf_bits(wo[1 * 128]);
        a[2]  = f2bf_bits(wo[2 * 128]); a[3]  = f2bf_bits(wo[3 * 128]);
        b2[0] = f2bf_bits(wo[4 * 128]); b2[1] = f2bf_bits(wo[5 * 128]);
        b2[2] = f2bf_bits(wo[6 * 128]); b2[3] = f2bf_bits(wo[7 * 128]);
        *(ushort4_t*)(Wot + (size_t)t * 8)     = a;
        *(ushort4_t*)(Wot + (size_t)t * 8 + 4) = b2;
        return;
    }

    const int tid = threadIdx.x;
    const int lane = tid & 63;
    const int i15 = lane & 15, quad = lane >> 4;
    const int wid = tid >> 6;
    const int wpart = wid & 1;
    const int pairIdx = wid >> 1;
    const int gw = blockIdx.x * 4 + wid;
    const int row0 = (gw >> 1) * 32;

    // ---- cooperative coalesced x staging (64 rows = this block's 2 pairs) ----
    {
        const float* xblk = x + (size_t)blockIdx.x * 64 * 128;
        #pragma unroll
        for (int it = 0; it < 8; ++it) {
            const int idx = (it * 256 + tid) * 4;
            const int row = idx >> 7, col = idx & 127;
            const float4 v = *(const float4*)(xblk + idx);
            ushort4_t s;
            s[0] = f2bf_bits(v.x); s[1] = f2bf_bits(v.y);
            s[2] = f2bf_bits(v.z); s[3] = f2bf_bits(v.w);
            *(ushort4_t*)(&xst[row][col]) = s;
        }
    }
    __syncthreads();

    short8_t af[2][4];
    #pragma unroll
    for (int rg = 0; rg < 2; ++rg)
        #pragma unroll
        for (int kc = 0; kc < 4; ++kc)
            af[rg][kc] = *(const short8_t*)(&xst[pairIdx * 32 + rg * 16 + i15][kc * 32 + quad * 8]);

    float4_t acc[2][12];
    #pragma unroll
    for (int rg = 0; rg < 2; ++rg)
        #pragma unroll
        for (int nt = 0; nt < 12; ++nt) acc[rg][nt] = (float4_t){0.f, 0.f, 0.f, 0.f};

    #pragma unroll
    for (int nt = 0; nt < 12; ++nt) {
        const int n = wpart * 192 + nt * 16 + i15;
        const float* wcol = W + n;                 // W[k][n] at k*384 + n
        #pragma unroll
        for (int kc = 0; kc < 4; ++kc) {
            const float* wk = wcol + (size_t)(kc * 32 + quad * 8) * 384;
            const float w0 = wk[0 * 384], w1 = wk[1 * 384];
            const float w2 = wk[2 * 384], w3 = wk[3 * 384];
            const float w4 = wk[4 * 384], w5 = wk[5 * 384];
            const float w6 = wk[6 * 384], w7 = wk[7 * 384];
            uint4_t up;
            up[0] = pk_bf16(w1, w0); up[1] = pk_bf16(w3, w2);
            up[2] = pk_bf16(w5, w4); up[3] = pk_bf16(w7, w6);
            const short8_t bf = *reinterpret_cast<const short8_t*>(&up);
            acc[0][nt] = __builtin_amdgcn_mfma_f32_16x16x32_bf16(af[0][kc], bf, acc[0][nt], 0, 0, 0);
            acc[1][nt] = __builtin_amdgcn_mfma_f32_16x16x32_bf16(af[1][kc], bf, acc[1][nt], 0, 0, 0);
        }
    }

    // 1/sqrt(32) * log2(e): attention uses exp2 directly
    const float scale = 0.17677669529663687f * 1.4426950408889634f;
    const int t = lane >> 2, c4 = lane & 3;

    #pragma unroll
    for (int rg = 0; rg < 2; ++rg) {
        const int r0 = row0 + rg * 16;
        const int b = r0 >> 10, t0 = r0 & 1023;
        if (wpart == 0) {
            ushort_t* Ls = qkA[pairIdx];
            #pragma unroll
            for (int nt = 0; nt < 12; ++nt) {
                const int col = nt * 16 + i15;
                const float sc = (nt < 8) ? scale : 1.f;
                #pragma unroll
                for (int r = 0; r < 4; ++r)
                    Ls[(quad * 4 + r) * 200 + col] = f2bf_bits(acc[rg][nt][r] * sc);
            }
            #pragma unroll
            for (int it = 0; it < 6; ++it) {
                const int col8 = it * 4 + c4;
                const ushort8_t v8 = *(const ushort8_t*)(Ls + t * 200 + col8 * 8);
                __hip_bfloat16* base = (it < 4) ? qws : kws;
                const int h = (it < 4) ? it : (it - 4);
                *(ushort8_t*)((ushort_t*)base +
                    ((size_t)(b * H_ + h) * T_ + t0 + t) * DH_ + c4 * 8) = v8;
            }
        } else {
            ushort_t* Ls = qkB[pairIdx];
            #pragma unroll
            for (int nt = 0; nt < 12; ++nt) {
                if (nt < 4) {
                    const int col = nt * 16 + i15;
                    #pragma unroll
                    for (int r = 0; r < 4; ++r)
                        Ls[(quad * 4 + r) * 72 + col] = f2bf_bits(acc[rg][nt][r]);
                } else {
                    const int ch = nt * 16 + i15 - 64;
                    const int h = ch >> 5, dh = ch & 31;
                    ushort4_t pk;
                    #pragma unroll
                    for (int r = 0; r < 4; ++r) pk[r] = f2bf_bits(acc[rg][nt][r]);
                    // chunk-fragment V layout:
                    // (g,l,j) -> dh=(g>>1)*16+(l&15), k=c*64+(g&1)*32+(l>>4)*8+j
                    const int k_ = t0 + quad * 4;
                    const int c_ = k_ >> 6;
                    const int g_ = ((k_ & 63) >> 5) | ((dh >> 4) << 1);
                    const int lp = (dh & 15) | (((k_ & 31) >> 3) << 4);
                    *(ushort4_t*)((ushort_t*)vtws +
                        (((size_t)(b * H_ + h) * 16 + c_) * 4 + g_) * 512 +
                        lp * 8 + (k_ & 7)) = pk;
                }
            }
            #pragma unroll
            for (int it = 0; it < 2; ++it) {
                const int col8 = it * 4 + c4;
                const ushort8_t v8 = *(const ushort8_t*)(Ls + t * 72 + col8 * 8);
                *(ushort8_t*)((ushort_t*)kws +
                    ((size_t)(b * H_ + 2 + it) * T_ + t0 + t) * DH_ + c4 * 8) = v8;
            }
        }
    }
}

// ------ Kernel 2: fused flash attention + output proj + residual + LN ------
// R14 body + NEW: epilogue x reads and out writes coalesced through LDS.
// plds (18.4KB) is dead after the main loop -> reused as a 32x132 f32 buffer
// (stride 132: all phases verified <=2-way bank aliasing = free). x loaded
// float4-coalesced into regs BEFORE the barrier (latency hides under O-write
// + barrier), staged to LDS; LN written in-place; all 4 waves then store out
// as fully-coalesced float4 (was: 64 scalar 4-segment instrs on 2 waves).
__global__ __launch_bounds__(256, 2) void attn_proj_ln(
    const ushort_t* __restrict__ qws, const ushort_t* __restrict__ kws,
    const ushort_t* __restrict__ vtws, const int* __restrict__ keys_length,
    const ushort_t* __restrict__ Wot, const float* __restrict__ x,
    const float* __restrict__ gamma, const float* __restrict__ beta,
    float* __restrict__ out)
{
    __shared__ ushort_t plds[4][32 * 72];  // per-head P tiles (18432 B)
    __shared__ ushort_t att[32 * 128];     // swizzled O strip (8192 B)

    const int wid = threadIdx.x >> 6;      // wave == head
    const int lane = threadIdx.x & 63;
    const int i15 = lane & 15, quad = lane >> 4;
    const int b = blockIdx.x & 31;
    const int st = 31 - (blockIdx.x >> 5); // heavy strips dispatch first
    const int qbase = st * 32;
    const int h = wid;
    const int bh = b * 4 + h;
    const int len = keys_length[b];

    const ushort_t* Qb = qws + (size_t)bh * T_ * DH_;
    const ushort_t* Kb = kws + (size_t)bh * T_ * DH_;
    const ushort_t* Vtb = vtws + (size_t)bh * 32768;  // 16 chunks x 4KB

    const short8_t qfA = *(const short8_t*)(Qb + (size_t)(qbase + i15) * DH_ + quad * 8);
    const short8_t qfB = *(const short8_t*)(Qb + (size_t)(qbase + 16 + i15) * DH_ + quad * 8);

    const int kend    = min(qbase + 32, len);
    const int nch     = (kend + 63) >> 6;       // >=1 since len>=1
    const int limAmax = min(qbase + 16, len);
    const int nfullA  = min(qbase + 1, len) >> 6;
    const int nfullB  = min(qbase + 17, len) >> 6;
    const int limA    = min(qbase + i15 + 1, len);      // per-lane: q = i15
    const int limB    = min(qbase + 16 + i15 + 1, len);

    ushort_t* pl = plds[h];

    float4_t oA0 = {0,0,0,0}, oA1 = {0,0,0,0}, oB0 = {0,0,0,0}, oB1 = {0,0,0,0};
    float laccA = 0.f, laccB = 0.f;
    const float4_t zero = {0,0,0,0};

    short8_t kf[4], vf[4];
    {   // preload chunk 0 (nch >= 1 always)
        #pragma unroll
        for (int g = 0; g < 4; ++g)
            kf[g] = *(const short8_t*)(Kb + (size_t)(g * 16 + i15) * DH_ + quad * 8);
        #pragma unroll
        for (int g = 0; g < 4; ++g)
            vf[g] = *(const short8_t*)(Vtb + g * 512 + lane * 8);
    }

    for (int c = 0; c < nch; ++c) {
        const int k0 = c * 64;
        const bool doA = (k0 < limAmax);        // wave-uniform

        // QK^T transposed: D[key][q]; q pre-scaled by log2e -> exp2 direct
        float4_t sB[4], sA[4];
        #pragma unroll
        for (int g = 0; g < 4; ++g)
            sB[g] = __builtin_amdgcn_mfma_f32_16x16x32_bf16(kf[g], qfB, zero, 0, 0, 0);
        if (doA) {
            #pragma unroll
            for (int g = 0; g < 4; ++g)
                sA[g] = __builtin_amdgcn_mfma_f32_16x16x32_bf16(kf[g], qfA, zero, 0, 0, 0);
        }

        // prefetch chunk c+1's K/V (latency hides under exp/LDS/PV below)
        short8_t kf2[4], vf2[4];
        const int c2 = c + 1;
        if (c2 < nch) {
            const int k2 = c2 * 64;
            #pragma unroll
            for (int g = 0; g < 4; ++g)
                kf2[g] = *(const short8_t*)(Kb + (size_t)(k2 + g * 16 + i15) * DH_ + quad * 8);
            #pragma unroll
            for (int g = 0; g < 4; ++g)
                vf2[g] = *(const short8_t*)(Vtb + (size_t)c2 * 2048 + g * 512 + lane * 8);
        }
        __builtin_amdgcn_sched_barrier(0);

        {
            const bool fullB = (c < nfullB);
            ushort_t* prow = pl + (16 + i15) * 72 + quad * 4;
            #pragma unroll
            for (int g = 0; g < 4; ++g) {
                float p0 = fast_exp2(sB[g][0]), p1 = fast_exp2(sB[g][1]);
                float p2 = fast_exp2(sB[g][2]), p3 = fast_exp2(sB[g][3]);
                if (!fullB) {
                    const int d = limB - (k0 + g * 16 + quad * 4);
                    p0 = (d > 0) ? p0 : 0.f; p1 = (d > 1) ? p1 : 0.f;
                    p2 = (d > 2) ? p2 : 0.f; p3 = (d > 3) ? p3 : 0.f;
                }
                laccB += (p0 + p1) + (p2 + p3);
                uint2 w; w.x = pk_bf16(p1, p0); w.y = pk_bf16(p3, p2);
                *(uint2*)(prow + g * 16) = w;
            }
        }
        if (doA) {
            const bool fullA = (c < nfullA);
            ushort_t* prow = pl + i15 * 72 + quad * 4;
            #pragma unroll
            for (int g = 0; g < 4; ++g) {
                float p0 = fast_exp2(sA[g][0]), p1 = fast_exp2(sA[g][1]);
                float p2 = fast_exp2(sA[g][2]), p3 = fast_exp2(sA[g][3]);
                if (!fullA) {
                    const int d = limA - (k0 + g * 16 + quad * 4);
                    p0 = (d > 0) ? p0 : 0.f; p1 = (d > 1) ? p1 : 0.f;
                    p2 = (d > 2) ? p2 : 0.f; p3 = (d > 3) ? p3 : 0.f;
                }
                laccA += (p0 + p1) + (p2 + p3);
                uint2 w; w.x = pk_bf16(p1, p0); w.y = pk_bf16(p3, p2);
                *(uint2*)(prow + g * 16) = w;
            }
        }

        // PV (shared vf frags)
        {
            const short8_t pfB0 = *(const short8_t*)(pl + (16 + i15) * 72 + quad * 8);
            const short8_t pfB1 = *(const short8_t*)(pl + (16 + i15) * 72 + 32 + quad * 8);
            oB0 = __builtin_amdgcn_mfma_f32_16x16x32_bf16(pfB0, vf[0], oB0, 0, 0, 0);
            oB0 = __builtin_amdgcn_mfma_f32_16x16x32_bf16(pfB1, vf[1], oB0, 0, 0, 0);
            oB1 = __builtin_amdgcn_mfma_f32_16x16x32_bf16(pfB0, vf[2], oB1, 0, 0, 0);
            oB1 = __builtin_amdgcn_mfma_f32_16x16x32_bf16(pfB1, vf[3], oB1, 0, 0, 0);
        }
        if (doA) {
            const short8_t pfA0 = *(const short8_t*)(pl + i15 * 72 + quad * 8);
            const short8_t pfA1 = *(const short8_t*)(pl + i15 * 72 + 32 + quad * 8);
            oA0 = __builtin_amdgcn_mfma_f32_16x16x32_bf16(pfA0, vf[0], oA0, 0, 0, 0);
            oA0 = __builtin_amdgcn_mfma_f32_16x16x32_bf16(pfA1, vf[1], oA0, 0, 0, 0);
            oA1 = __builtin_amdgcn_mfma_f32_16x16x32_bf16(pfA0, vf[2], oA1, 0, 0, 0);
            oA1 = __builtin_amdgcn_mfma_f32_16x16x32_bf16(pfA1, vf[3], oA1, 0, 0, 0);
        }

        if (c2 < nch) {
            #pragma unroll
            for (int g = 0; g < 4; ++g) { kf[g] = kf2[g]; vf[g] = vf2[g]; }
        }
    }

    // full l per q (sum across quads)
    laccA += __shfl_xor(laccA, 16, 64); laccA += __shfl_xor(laccA, 32, 64);
    laccB += __shfl_xor(laccB, 16, 64); laccB += __shfl_xor(laccB, 32, 64);

    // write normalized O tile to swizzled LDS (byte ^= (row&7)<<4)
    #pragma unroll
    for (int r = 0; r < 4; ++r) {
        const int q = quad * 4 + r;
        const float invA = 1.f / __shfl(laccA, q, 64);
        const float invB = 1.f / __shfl(laccB, q, 64);
        const int colL = h * 32 + i15, colH = h * 32 + 16 + i15;
        char* ab = (char*)att;
        *(ushort_t*)(ab + ((q * 256 + colL * 2) ^ ((q & 7) << 4)))        = f2bf_bits(oA0[r] * invA);
        *(ushort_t*)(ab + ((q * 256 + colH * 2) ^ ((q & 7) << 4)))        = f2bf_bits(oA1[r] * invA);
        *(ushort_t*)(ab + (((16 + q) * 256 + colL * 2) ^ ((q & 7) << 4))) = f2bf_bits(oB0[r] * invB);
        *(ushort_t*)(ab + (((16 + q) * 256 + colH * 2) ^ ((q & 7) << 4))) = f2bf_bits(oB1[r] * invB);
    }

    // cooperative coalesced residual-x prefetch (issued BEFORE the barrier:
    // HBM/L2 latency hides under O-writes + barrier wait)
    float4 xf[4];
    {
        const float* xblk = x + ((size_t)b * T_ + qbase) * 128;
        #pragma unroll
        for (int i = 0; i < 4; ++i)
            xf[i] = *(const float4*)(xblk + (i * 256 + threadIdx.x) * 4);
    }
    __syncthreads();

    // stage x into LDS f32 buffer (plds dead; stride 132 -> <=2-way aliasing)
    float* xb = (float*)(&plds[0][0]);     // 32 x 132 floats = 16896 B
    {
        #pragma unroll
        for (int i = 0; i < 4; ++i) {
            const int idx = (i * 256 + threadIdx.x) * 4;
            const int row = idx >> 7, col = idx & 127;
            *(float4*)(xb + row * 132 + col) = xf[i];
        }
    }
    __syncthreads();

    // ---- proj + residual + LN: waves 0,1 take 16 rows each ----
    if (wid < 2) {
        const int lr = wid * 16 + i15;
        short8_t af[4];
        #pragma unroll
        for (int kc = 0; kc < 4; ++kc)
            af[kc] = *(const short8_t*)((const char*)att +
                ((lr * 256 + kc * 64 + quad * 16) ^ ((lr & 7) << 4)));

        float4_t acc[8];
        #pragma unroll
        for (int nt = 0; nt < 8; ++nt) acc[nt] = (float4_t){0.f, 0.f, 0.f, 0.f};

        // fragment-layout Wot: contiguous 1KB per (nt,kc) wave load
        #pragma unroll
        for (int nt = 0; nt < 8; ++nt) {
            #pragma unroll
            for (int kc = 0; kc < 4; ++kc) {
                const short8_t bf = *(const short8_t*)(Wot +
                    (size_t)((nt * 4 + kc) * 64 + lane) * 8);
                acc[nt] = __builtin_amdgcn_mfma_f32_16x16x32_bf16(af[kc], bf, acc[nt], 0, 0, 0);
            }
        }

        float g[8], be[8];
        #pragma unroll
        for (int nt = 0; nt < 8; ++nt) {
            g[nt] = gamma[nt * 16 + i15];
            be[nt] = beta[nt * 16 + i15];
        }

        #pragma unroll
        for (int r = 0; r < 4; ++r) {
            const int row = wid * 16 + quad * 4 + r;
            float y[8];
            float s1 = 0.f, s2 = 0.f;
            #pragma unroll
            for (int nt = 0; nt < 8; ++nt) {
                y[nt] = acc[nt][r] + xb[row * 132 + nt * 16 + i15];
                s1 += y[nt];
                s2 += y[nt] * y[nt];
            }
            #pragma unroll
            for (int off = 1; off < 16; off <<= 1) {
                s1 += __shfl_xor(s1, off, 64);
                s2 += __shfl_xor(s2, off, 64);
            }
            const float mean = s1 * (1.f / 128.f);
            const float var = s2 * (1.f / 128.f) - mean * mean;
            const float rstd = rsqrtf(var + 1e-9f);
            // in-place: each (row,col) slot is read & written by the same lane
            #pragma unroll
            for (int nt = 0; nt < 8; ++nt)
                xb[row * 132 + nt * 16 + i15] = (y[nt] - mean) * rstd * g[nt] + be[nt];
        }
    }
    __syncthreads();

    // cooperative fully-coalesced out store (all 4 waves)
    {
        float* outb = out + ((size_t)b * T_ + qbase) * 128;
        #pragma unroll
        for (int i = 0; i < 4; ++i) {
            const int idx = (i * 256 + threadIdx.x) * 4;
            const int row = idx >> 7, col = idx & 127;
            *(float4*)(outb + idx) = *(const float4*)(xb + row * 132 + col);
        }
    }
}

extern "C" void kernel_launch(void* const* d_in, const int* in_sizes, int n_in,
                              void* d_out, int out_size, void* d_ws, size_t ws_size,
                              hipStream_t stream) {
    const float* x      = (const float*)d_in[0];
    const int* keys_len = (const int*)d_in[1];
    const float* W      = (const float*)d_in[2];
    const float* Wo     = (const float*)d_in[3];
    const float* gamma  = (const float*)d_in[4];
    const float* beta   = (const float*)d_in[5];
    float* out          = (float*)d_out;  // f32 output (proven round 5)

    // ws: q | k | vt(chunk-frag layout) | Wot(frag layout, 32 KB)
    const size_t seg = (size_t)B_ * H_ * T_ * DH_;
    __hip_bfloat16* qws  = (__hip_bfloat16*)d_ws;
    __hip_bfloat16* kws  = qws + seg;
    __hip_bfloat16* vtws = qws + 2 * seg;
    ushort_t* Wot = (ushort_t*)(qws + 3 * seg);

    // 512 main blocks (32 rows/wave) + 8 tail blocks (Wo -> frag-layout Wot)
    qkv_mfma<<<520, 256, 0, stream>>>(x, W, Wo, qws, kws, vtws, Wot);
    // 1024 blocks = 32 b x 32 strips (R7 mapping, best measured)
    attn_proj_ln<<<B_ * (T_ / 32), 256, 0, stream>>>(
        (const ushort_t*)qws, (const ushort_t*)kws, (const ushort_t*)vtws,
        keys_len, Wot, x, gamma, beta, out);
}

// Round 16
// 113.940 us; speedup vs baseline: 1.0843x; 1.0843x over previous
//
#include <hip/hip_runtime.h>
#include <hip/hip_bf16.h>

#define B_ 32
#define T_ 1024
#define D_ 128
#define H_ 4
#define DH_ 32

typedef unsigned short ushort_t;
typedef unsigned int uint_t;
typedef unsigned short ushort4_t __attribute__((ext_vector_type(4)));
typedef unsigned short ushort8_t __attribute__((ext_vector_type(8)));
typedef short short8_t __attribute__((ext_vector_type(8)));
typedef float float4_t __attribute__((ext_vector_type(4)));
typedef unsigned int uint4_t __attribute__((ext_vector_type(4)));

__device__ __forceinline__ ushort_t f2bf_bits(float f) {
    __hip_bfloat16 h = __float2bfloat16(f);
    return *reinterpret_cast<ushort_t*>(&h);
}
// pack trunc-bf16(hi)<<16 | trunc-bf16(lo) in one v_perm_b32
__device__ __forceinline__ uint_t pk_bf16(float hi, float lo) {
    return __builtin_amdgcn_perm(__float_as_uint(hi), __float_as_uint(lo),
                                 0x07060302u);
}
#if __has_builtin(__builtin_amdgcn_exp2f)
__device__ __forceinline__ float fast_exp2(float x) { return __builtin_amdgcn_exp2f(x); }
#else
__device__ __forceinline__ float fast_exp2(float x) { return exp2f(x); }
#endif

// ---------------- Kernel 1: MFMA QKV projection, 32 rows/wave --------------
// R14 version (x staged via LDS; raw W + pk_bf16; chunk-fragment V layout;
// tail blocks write Wo in MFMA-fragment layout). R15's epilogue-LDS change
// regressed (-9us: 2 extra barriers > 2x store-coalescing win) — reverted.
__global__ __launch_bounds__(256) void qkv_mfma(
    const float* __restrict__ x, const float* __restrict__ W,
    const float* __restrict__ Wo,
    __hip_bfloat16* __restrict__ qws, __hip_bfloat16* __restrict__ kws,
    __hip_bfloat16* __restrict__ vtws, ushort_t* __restrict__ Wot)
{
    __shared__ ushort_t xst[64][136];      // 17408 B staged x (bf16)
    __shared__ ushort_t qkA[2][16 * 200];
    __shared__ ushort_t qkB[2][16 * 72];

    if (blockIdx.x >= 512) {   // grid tail: Wo -> fragment layout (8 blocks)
        const int t = (blockIdx.x - 512) * 256 + threadIdx.x;  // 0..2047
        const int nt = t >> 8, kc = (t >> 6) & 3, lane = t & 63;
        const int tq = lane >> 4, ti = lane & 15;
        const int n = nt * 16 + ti;
        // frag element j = Wo[kc*32 + tq*8 + j][n], j=0..7
        const float* wo = Wo + (size_t)(kc * 32 + tq * 8) * 128 + n;
        ushort4_t a, b2;
        a[0]  = f2bf_bits(wo[0 * 128]); a[1]  = f2bf_bits(wo[1 * 128]);
        a[2]  = f2bf_bits(wo[2 * 128]); a[3]  = f2bf_bits(wo[3 * 128]);
        b2[0] = f2bf_bits(wo[4 * 128]); b2[1] = f2bf_bits(wo[5 * 128]);
        b2[2] = f2bf_bits(wo[6 * 128]); b2[3] = f2bf_bits(wo[7 * 128]);
        *(ushort4_t*)(Wot + (size_t)t * 8)     = a;
        *(ushort4_t*)(Wot + (size_t)t * 8 + 4) = b2;
        return;
    }

    const int tid = threadIdx.x;
    const int lane = tid & 63;
    const int i15 = lane & 15, quad = lane >> 4;
    const int wid = tid >> 6;
    const int wpart = wid & 1;
    const int pairIdx = wid >> 1;
    const int gw = blockIdx.x * 4 + wid;
    const int row0 = (gw >> 1) * 32;

    // ---- cooperative coalesced x staging (64 rows = this block's 2 pairs) ----
    {
        const float* xblk = x + (size_t)blockIdx.x * 64 * 128;
        #pragma unroll
        for (int it = 0; it < 8; ++it) {
            const int idx = (it * 256 + tid) * 4;
            const int row = idx >> 7, col = idx & 127;
            const float4 v = *(const float4*)(xblk + idx);
            ushort4_t s;
            s[0] = f2bf_bits(v.x); s[1] = f2bf_bits(v.y);
            s[2] = f2bf_bits(v.z); s[3] = f2bf_bits(v.w);
            *(ushort4_t*)(&xst[row][col]) = s;
        }
    }
    __syncthreads();

    short8_t af[2][4];
    #pragma unroll
    for (int rg = 0; rg < 2; ++rg)
        #pragma unroll
        for (int kc = 0; kc < 4; ++kc)
            af[rg][kc] = *(const short8_t*)(&xst[pairIdx * 32 + rg * 16 + i15][kc * 32 + quad * 8]);

    float4_t acc[2][12];
    #pragma unroll
    for (int rg = 0; rg < 2; ++rg)
        #pragma unroll
        for (int nt = 0; nt < 12; ++nt) acc[rg][nt] = (float4_t){0.f, 0.f, 0.f, 0.f};

    #pragma unroll
    for (int nt = 0; nt < 12; ++nt) {
        const int n = wpart * 192 + nt * 16 + i15;
        const float* wcol = W + n;                 // W[k][n] at k*384 + n
        #pragma unroll
        for (int kc = 0; kc < 4; ++kc) {
            const float* wk = wcol + (size_t)(kc * 32 + quad * 8) * 384;
            const float w0 = wk[0 * 384], w1 = wk[1 * 384];
            const float w2 = wk[2 * 384], w3 = wk[3 * 384];
            const float w4 = wk[4 * 384], w5 = wk[5 * 384];
            const float w6 = wk[6 * 384], w7 = wk[7 * 384];
            uint4_t up;
            up[0] = pk_bf16(w1, w0); up[1] = pk_bf16(w3, w2);
            up[2] = pk_bf16(w5, w4); up[3] = pk_bf16(w7, w6);
            const short8_t bf = *reinterpret_cast<const short8_t*>(&up);
            acc[0][nt] = __builtin_amdgcn_mfma_f32_16x16x32_bf16(af[0][kc], bf, acc[0][nt], 0, 0, 0);
            acc[1][nt] = __builtin_amdgcn_mfma_f32_16x16x32_bf16(af[1][kc], bf, acc[1][nt], 0, 0, 0);
        }
    }

    // 1/sqrt(32) * log2(e): attention uses exp2 directly
    const float scale = 0.17677669529663687f * 1.4426950408889634f;
    const int t = lane >> 2, c4 = lane & 3;

    #pragma unroll
    for (int rg = 0; rg < 2; ++rg) {
        const int r0 = row0 + rg * 16;
        const int b = r0 >> 10, t0 = r0 & 1023;
        if (wpart == 0) {
            ushort_t* Ls = qkA[pairIdx];
            #pragma unroll
            for (int nt = 0; nt < 12; ++nt) {
                const int col = nt * 16 + i15;
                const float sc = (nt < 8) ? scale : 1.f;
                #pragma unroll
                for (int r = 0; r < 4; ++r)
                    Ls[(quad * 4 + r) * 200 + col] = f2bf_bits(acc[rg][nt][r] * sc);
            }
            #pragma unroll
            for (int it = 0; it < 6; ++it) {
                const int col8 = it * 4 + c4;
                const ushort8_t v8 = *(const ushort8_t*)(Ls + t * 200 + col8 * 8);
                __hip_bfloat16* base = (it < 4) ? qws : kws;
                const int h = (it < 4) ? it : (it - 4);
                *(ushort8_t*)((ushort_t*)base +
                    ((size_t)(b * H_ + h) * T_ + t0 + t) * DH_ + c4 * 8) = v8;
            }
        } else {
            ushort_t* Ls = qkB[pairIdx];
            #pragma unroll
            for (int nt = 0; nt < 12; ++nt) {
                if (nt < 4) {
                    const int col = nt * 16 + i15;
                    #pragma unroll
                    for (int r = 0; r < 4; ++r)
                        Ls[(quad * 4 + r) * 72 + col] = f2bf_bits(acc[rg][nt][r]);
                } else {
                    const int ch = nt * 16 + i15 - 64;
                    const int h = ch >> 5, dh = ch & 31;
                    ushort4_t pk;
                    #pragma unroll
                    for (int r = 0; r < 4; ++r) pk[r] = f2bf_bits(acc[rg][nt][r]);
                    // chunk-fragment V layout:
                    // (g,l,j) -> dh=(g>>1)*16+(l&15), k=c*64+(g&1)*32+(l>>4)*8+j
                    const int k_ = t0 + quad * 4;
                    const int c_ = k_ >> 6;
                    const int g_ = ((k_ & 63) >> 5) | ((dh >> 4) << 1);
                    const int lp = (dh & 15) | (((k_ & 31) >> 3) << 4);
                    *(ushort4_t*)((ushort_t*)vtws +
                        (((size_t)(b * H_ + h) * 16 + c_) * 4 + g_) * 512 +
                        lp * 8 + (k_ & 7)) = pk;
                }
            }
            #pragma unroll
            for (int it = 0; it < 2; ++it) {
                const int col8 = it * 4 + c4;
                const ushort8_t v8 = *(const ushort8_t*)(Ls + t * 72 + col8 * 8);
                *(ushort8_t*)((ushort_t*)kws +
                    ((size_t)(b * H_ + 2 + it) * T_ + t0 + t) * DH_ + c4 * 8) = v8;
            }
        }
    }
}

// ------ Kernel 2: fused flash attention + output proj + residual + LN ------
// R14 version byte-identical (best measured: total 114.3).
__global__ __launch_bounds__(256, 2) void attn_proj_ln(
    const ushort_t* __restrict__ qws, const ushort_t* __restrict__ kws,
    const ushort_t* __restrict__ vtws, const int* __restrict__ keys_length,
    const ushort_t* __restrict__ Wot, const float* __restrict__ x,
    const float* __restrict__ gamma, const float* __restrict__ beta,
    float* __restrict__ out)
{
    __shared__ ushort_t plds[4][32 * 72];  // per-head P tiles (18432 B)
    __shared__ ushort_t att[32 * 128];     // swizzled O strip (8192 B)

    const int wid = threadIdx.x >> 6;      // wave == head
    const int lane = threadIdx.x & 63;
    const int i15 = lane & 15, quad = lane >> 4;
    const int b = blockIdx.x & 31;
    const int st = 31 - (blockIdx.x >> 5); // heavy strips dispatch first
    const int qbase = st * 32;
    const int h = wid;
    const int bh = b * 4 + h;
    const int len = keys_length[b];

    const ushort_t* Qb = qws + (size_t)bh * T_ * DH_;
    const ushort_t* Kb = kws + (size_t)bh * T_ * DH_;
    const ushort_t* Vtb = vtws + (size_t)bh * 32768;  // 16 chunks x 4KB

    const short8_t qfA = *(const short8_t*)(Qb + (size_t)(qbase + i15) * DH_ + quad * 8);
    const short8_t qfB = *(const short8_t*)(Qb + (size_t)(qbase + 16 + i15) * DH_ + quad * 8);

    const int kend    = min(qbase + 32, len);
    const int nch     = (kend + 63) >> 6;       // >=1 since len>=1
    const int limAmax = min(qbase + 16, len);
    const int nfullA  = min(qbase + 1, len) >> 6;
    const int nfullB  = min(qbase + 17, len) >> 6;
    const int limA    = min(qbase + i15 + 1, len);      // per-lane: q = i15
    const int limB    = min(qbase + 16 + i15 + 1, len);

    ushort_t* pl = plds[h];

    float4_t oA0 = {0,0,0,0}, oA1 = {0,0,0,0}, oB0 = {0,0,0,0}, oB1 = {0,0,0,0};
    float laccA = 0.f, laccB = 0.f;
    const float4_t zero = {0,0,0,0};

    short8_t kf[4], vf[4];
    {   // preload chunk 0 (nch >= 1 always)
        #pragma unroll
        for (int g = 0; g < 4; ++g)
            kf[g] = *(const short8_t*)(Kb + (size_t)(g * 16 + i15) * DH_ + quad * 8);
        #pragma unroll
        for (int g = 0; g < 4; ++g)
            vf[g] = *(const short8_t*)(Vtb + g * 512 + lane * 8);
    }

    for (int c = 0; c < nch; ++c) {
        const int k0 = c * 64;
        const bool doA = (k0 < limAmax);        // wave-uniform

        // QK^T transposed: D[key][q]; q pre-scaled by log2e -> exp2 direct
        float4_t sB[4], sA[4];
        #pragma unroll
        for (int g = 0; g < 4; ++g)
            sB[g] = __builtin_amdgcn_mfma_f32_16x16x32_bf16(kf[g], qfB, zero, 0, 0, 0);
        if (doA) {
            #pragma unroll
            for (int g = 0; g < 4; ++g)
                sA[g] = __builtin_amdgcn_mfma_f32_16x16x32_bf16(kf[g], qfA, zero, 0, 0, 0);
        }

        // prefetch chunk c+1's K/V (latency hides under exp/LDS/PV below)
        short8_t kf2[4], vf2[4];
        const int c2 = c + 1;
        if (c2 < nch) {
            const int k2 = c2 * 64;
            #pragma unroll
            for (int g = 0; g < 4; ++g)
                kf2[g] = *(const short8_t*)(Kb + (size_t)(k2 + g * 16 + i15) * DH_ + quad * 8);
            #pragma unroll
            for (int g = 0; g < 4; ++g)
                vf2[g] = *(const short8_t*)(Vtb + (size_t)c2 * 2048 + g * 512 + lane * 8);
        }
        __builtin_amdgcn_sched_barrier(0);

        {
            const bool fullB = (c < nfullB);
            ushort_t* prow = pl + (16 + i15) * 72 + quad * 4;
            #pragma unroll
            for (int g = 0; g < 4; ++g) {
                float p0 = fast_exp2(sB[g][0]), p1 = fast_exp2(sB[g][1]);
                float p2 = fast_exp2(sB[g][2]), p3 = fast_exp2(sB[g][3]);
                if (!fullB) {
                    const int d = limB - (k0 + g * 16 + quad * 4);
                    p0 = (d > 0) ? p0 : 0.f; p1 = (d > 1) ? p1 : 0.f;
                    p2 = (d > 2) ? p2 : 0.f; p3 = (d > 3) ? p3 : 0.f;
                }
                laccB += (p0 + p1) + (p2 + p3);
                uint2 w; w.x = pk_bf16(p1, p0); w.y = pk_bf16(p3, p2);
                *(uint2*)(prow + g * 16) = w;
            }
        }
        if (doA) {
            const bool fullA = (c < nfullA);
            ushort_t* prow = pl + i15 * 72 + quad * 4;
            #pragma unroll
            for (int g = 0; g < 4; ++g) {
                float p0 = fast_exp2(sA[g][0]), p1 = fast_exp2(sA[g][1]);
                float p2 = fast_exp2(sA[g][2]), p3 = fast_exp2(sA[g][3]);
                if (!fullA) {
                    const int d = limA - (k0 + g * 16 + quad * 4);
                    p0 = (d > 0) ? p0 : 0.f; p1 = (d > 1) ? p1 : 0.f;
                    p2 = (d > 2) ? p2 : 0.f; p3 = (d > 3) ? p3 : 0.f;
                }
                laccA += (p0 + p1) + (p2 + p3);
                uint2 w; w.x = pk_bf16(p1, p0); w.y = pk_bf16(p3, p2);
                *(uint2*)(prow + g * 16) = w;
            }
        }

        // PV (shared vf frags)
        {
            const short8_t pfB0 = *(const short8_t*)(pl + (16 + i15) * 72 + quad * 8);
            const short8_t pfB1 = *(const short8_t*)(pl + (16 + i15) * 72 + 32 + quad * 8);
            oB0 = __builtin_amdgcn_mfma_f32_16x16x32_bf16(pfB0, vf[0], oB0, 0, 0, 0);
            oB0 = __builtin_amdgcn_mfma_f32_16x16x32_bf16(pfB1, vf[1], oB0, 0, 0, 0);
            oB1 = __builtin_amdgcn_mfma_f32_16x16x32_bf16(pfB0, vf[2], oB1, 0, 0, 0);
            oB1 = __builtin_amdgcn_mfma_f32_16x16x32_bf16(pfB1, vf[3], oB1, 0, 0, 0);
        }
        if (doA) {
            const short8_t pfA0 = *(const short8_t*)(pl + i15 * 72 + quad * 8);
            const short8_t pfA1 = *(const short8_t*)(pl + i15 * 72 + 32 + quad * 8);
            oA0 = __builtin_amdgcn_mfma_f32_16x16x32_bf16(pfA0, vf[0], oA0, 0, 0, 0);
            oA0 = __builtin_amdgcn_mfma_f32_16x16x32_bf16(pfA1, vf[1], oA0, 0, 0, 0);
            oA1 = __builtin_amdgcn_mfma_f32_16x16x32_bf16(pfA0, vf[2], oA1, 0, 0, 0);
            oA1 = __builtin_amdgcn_mfma_f32_16x16x32_bf16(pfA1, vf[3], oA1, 0, 0, 0);
        }

        if (c2 < nch) {
            #pragma unroll
            for (int g = 0; g < 4; ++g) { kf[g] = kf2[g]; vf[g] = vf2[g]; }
        }
    }

    // full l per q (sum across quads)
    laccA += __shfl_xor(laccA, 16, 64); laccA += __shfl_xor(laccA, 32, 64);
    laccB += __shfl_xor(laccB, 16, 64); laccB += __shfl_xor(laccB, 32, 64);

    // write normalized O tile to swizzled LDS (byte ^= (row&7)<<4)
    #pragma unroll
    for (int r = 0; r < 4; ++r) {
        const int q = quad * 4 + r;
        const float invA = 1.f / __shfl(laccA, q, 64);
        const float invB = 1.f / __shfl(laccB, q, 64);
        const int colL = h * 32 + i15, colH = h * 32 + 16 + i15;
        char* ab = (char*)att;
        *(ushort_t*)(ab + ((q * 256 + colL * 2) ^ ((q & 7) << 4)))        = f2bf_bits(oA0[r] * invA);
        *(ushort_t*)(ab + ((q * 256 + colH * 2) ^ ((q & 7) << 4)))        = f2bf_bits(oA1[r] * invA);
        *(ushort_t*)(ab + (((16 + q) * 256 + colL * 2) ^ ((q & 7) << 4))) = f2bf_bits(oB0[r] * invB);
        *(ushort_t*)(ab + (((16 + q) * 256 + colH * 2) ^ ((q & 7) << 4))) = f2bf_bits(oB1[r] * invB);
    }
    __syncthreads();

    // ---- proj + residual + LN: waves 0,1 take 16 rows each ----
    if (wid < 2) {
        const int lr = wid * 16 + i15;
        short8_t af[4];
        #pragma unroll
        for (int kc = 0; kc < 4; ++kc)
            af[kc] = *(const short8_t*)((const char*)att +
                ((lr * 256 + kc * 64 + quad * 16) ^ ((lr & 7) << 4)));

        float4_t acc[8];
        #pragma unroll
        for (int nt = 0; nt < 8; ++nt) acc[nt] = (float4_t){0.f, 0.f, 0.f, 0.f};

        // fragment-layout Wot: contiguous 1KB per (nt,kc) wave load
        #pragma unroll
        for (int nt = 0; nt < 8; ++nt) {
            #pragma unroll
            for (int kc = 0; kc < 4; ++kc) {
                const short8_t bf = *(const short8_t*)(Wot +
                    (size_t)((nt * 4 + kc) * 64 + lane) * 8);
                acc[nt] = __builtin_amdgcn_mfma_f32_16x16x32_bf16(af[kc], bf, acc[nt], 0, 0, 0);
            }
        }

        float g[8], be[8];
        #pragma unroll
        for (int nt = 0; nt < 8; ++nt) {
            g[nt] = gamma[nt * 16 + i15];
            be[nt] = beta[nt * 16 + i15];
        }

        const int m0 = b * T_ + qbase + wid * 16;
        #pragma unroll
        for (int r = 0; r < 4; ++r) {
            const int m = m0 + quad * 4 + r;
            float y[8];
            float s1 = 0.f, s2 = 0.f;
            #pragma unroll
            for (int nt = 0; nt < 8; ++nt) {
                y[nt] = acc[nt][r] + x[(size_t)m * 128 + nt * 16 + i15];
                s1 += y[nt];
                s2 += y[nt] * y[nt];
            }
            #pragma unroll
            for (int off = 1; off < 16; off <<= 1) {
                s1 += __shfl_xor(s1, off, 64);
                s2 += __shfl_xor(s2, off, 64);
            }
            const float mean = s1 * (1.f / 128.f);
            const float var = s2 * (1.f / 128.f) - mean * mean;
            const float rstd = rsqrtf(var + 1e-9f);
            #pragma unroll
            for (int nt = 0; nt < 8; ++nt)
                out[(size_t)m * 128 + nt * 16 + i15] = (y[nt] - mean) * rstd * g[nt] + be[nt];
        }
    }
}

extern "C" void kernel_launch(void* const* d_in, const int* in_sizes, int n_in,
                              void* d_out, int out_size, void* d_ws, size_t ws_size,
                              hipStream_t stream) {
    const float* x      = (const float*)d_in[0];
    const int* keys_len = (const int*)d_in[1];
    const float* W      = (const float*)d_in[2];
    const float* Wo     = (const float*)d_in[3];
    const float* gamma  = (const float*)d_in[4];
    const float* beta   = (const float*)d_in[5];
    float* out          = (float*)d_out;  // f32 output (proven round 5)

    // ws: q | k | vt(chunk-frag layout) | Wot(frag layout, 32 KB)
    const size_t seg = (size_t)B_ * H_ * T_ * DH_;
    __hip_bfloat16* qws  = (__hip_bfloat16*)d_ws;
    __hip_bfloat16* kws  = qws + seg;
    __hip_bfloat16* vtws = qws + 2 * seg;
    ushort_t* Wot = (ushort_t*)(qws + 3 * seg);

    // 512 main blocks (32 rows/wave) + 8 tail blocks (Wo -> frag-layout Wot)
    qkv_mfma<<<520, 256, 0, stream>>>(x, W, Wo, qws, kws, vtws, Wot);
    // 1024 blocks = 32 b x 32 strips (R7 mapping, best measured)
    attn_proj_ln<<<B_ * (T_ / 32), 256, 0, stream>>>(
        (const ushort_t*)qws, (const ushort_t*)kws, (const ushort_t*)vtws,
        keys_len, Wot, x, gamma, beta, out);
}